// Round 1
// 619.595 us; speedup vs baseline: 1.0135x; 1.0135x over previous
//
#include <hip/hip_runtime.h>
#include <math.h>

#define BB   16
#define NN   32768
#define GG   128
#define KK   64
#define EDD  384
#define NT1  1024
#define PPT  32   // NN / NT1 (k_grp topk phase)
#define SB   4    // k_fps blocks per batch
#define SP   (NN / SB)   // 8192 points per k_fps block
#define JP   (SP / NT1)  // 8 points/thread, register-resident

// ---- workspace layout (float offsets) ----
#define WS_GC     0          // [16][2][3]      = 96     (c0, cm per batch)
#define WS_F2     6240       // [32][256][64]   = 524288
#define WS_FG     530528     // [32][256]       = 8192
#define WS_F4     538720     // [32][512][64]   = 1048576
#define WS_SYNC   1587296    // u64 [2 parity][16 batch][64 wave] = 16 KB used

__device__ __forceinline__ float sq3(float a, float b, float c) {
  // matches np: ((a*a + b*b) + c*c), no FMA contraction
  return __fadd_rn(__fadd_rn(__fmul_rn(a, a), __fmul_rn(b, b)), __fmul_rn(c, c));
}
__device__ __forceinline__ float dot3(float ax, float ay, float az,
                                      float bx, float by, float bz) {
  return __fadd_rn(__fadd_rn(__fmul_rn(ax, bx), __fmul_rn(ay, by)), __fmul_rn(az, bz));
}
__device__ __forceinline__ unsigned long long shfl_xor_u64(unsigned long long v,
                                                           int off) {
  unsigned lo = (unsigned)v, hi = (unsigned)(v >> 32);
  lo = __shfl_xor(lo, off);
  hi = __shfl_xor(hi, off);
  return ((unsigned long long)hi << 32) | lo;
}

// ---------------------------------------------------------------------------
// Kernel 1: FPS. 4 blocks/batch; coords + dist fully register-resident
// (8 pts/thread x {x,y,z,dist} = 32 VGPRs) -> zero LDS traffic in round loop.
// Sync per round: each wave's lane-0 publishes its 64-lane-reduced packed
// candidate (d_bits<<32 | round<<16 | (0xFFFF-idx)) straight to a global slot
// (relaxed agent atomic -- value-only protocol, no acq/rel cache ops needed).
// Wave 0 spins on the batch's 64 slots (one lane each) until every tag ==
// round, butterflies to the global winner, broadcasts via 1 LDS word +
// single barrier. Slots double-buffered by round parity: a wave reaches its
// round-(it+2) store only after barrier(it+1), which requires every block's
// reader to have consumed round it -> no clobber, and tag-check makes stale
// reads impossible. 64 blocks co-resident (VGPR<=128, ~2KB LDS) -> no
// deadlock. Tie-break: u64 max with (0xFFFF-idx) low bits = np.argmax
// first-max rule (smallest global index wins ties).
// ---------------------------------------------------------------------------
__global__ void __launch_bounds__(NT1) k_fps(const float* __restrict__ points,
                                             float* __restrict__ out,
                                             float* __restrict__ ws) {
  __shared__ float cent[GG * 3];
  __shared__ float darr[GG];
  __shared__ int msh[1];
  __shared__ unsigned long long winp;

  const int gb  = blockIdx.x;
  const int b   = gb >> 2, blk = gb & 3;
  const int t   = threadIdx.x;
  const int wave = t >> 6, lane = t & 63;
  const float* P = points + (size_t)b * NN * 3;
  const int base = blk * SP;
  unsigned long long* slots = (unsigned long long*)(ws + WS_SYNC);

  // stage this thread's 8 points into registers
  float px[JP], py[JP], pz[JP], dist[JP];
#pragma unroll
  for (int j = 0; j < JP; ++j) {
    const float* pp = P + (size_t)(base + t + j * NT1) * 3;
    px[j] = pp[0]; py[j] = pp[1]; pz[j] = pp[2];
    dist[j] = INFINITY;
  }
  float cx = P[0], cy = P[1], cz = P[2];  // centroid 0 = point 0
  if (blk == 0 && t == 0) { cent[0] = cx; cent[1] = cy; cent[2] = cz; }

  const int wslot = blk * 16 + wave;      // 0..63 wave id within batch
  for (int it = 1; it < GG; ++it) {
    // local update + per-thread best (strict > keeps first max, j ascending)
    float bd = -INFINITY; int bj = 0;
#pragma unroll
    for (int j = 0; j < JP; ++j) {
      float dx = __fsub_rn(px[j], cx);
      float dy = __fsub_rn(py[j], cy);
      float dz = __fsub_rn(pz[j], cz);
      float d  = __fadd_rn(__fadd_rn(__fmul_rn(dx, dx), __fmul_rn(dy, dy)),
                           __fmul_rn(dz, dz));
      float nd = fminf(dist[j], d);
      dist[j] = nd;
      if (nd > bd) { bd = nd; bj = j; }
    }
    // pack: [d_bits | it | 0xFFFF - global_idx]  (idx<32768 fits 15 bits)
    unsigned lo = ((unsigned)it << 16) |
                  (unsigned)(0xFFFF - (base + t + bj * NT1));
    unsigned long long bp =
        ((unsigned long long)__float_as_uint(bd) << 32) | lo;
#pragma unroll
    for (int off = 1; off < 64; off <<= 1) {
      unsigned long long o = shfl_xor_u64(bp, off);
      if (o > bp) bp = o;
    }
    unsigned long long* sl = slots + ((size_t)(it & 1) * 16 + b) * 64;
    if (lane == 0)
      __hip_atomic_store(&sl[wslot], bp, __ATOMIC_RELAXED,
                         __HIP_MEMORY_SCOPE_AGENT);
    if (wave == 0) {
      unsigned long long o;
      do {
        o = __hip_atomic_load(&sl[lane], __ATOMIC_RELAXED,
                              __HIP_MEMORY_SCOPE_AGENT);
      } while ((unsigned)((o >> 16) & 0xFFFF) != (unsigned)it);
#pragma unroll
      for (int off = 1; off < 64; off <<= 1) {
        unsigned long long oo = shfl_xor_u64(o, off);
        if (oo > o) o = oo;
      }
      if (lane == 0) winp = o;
    }
    __syncthreads();  // winner visible to all waves of this block
    unsigned long long w = winp;
    int sv = 0xFFFF - (int)(w & 0xFFFF);
    const float* wp = P + (size_t)sv * 3;  // wave-uniform -> broadcast load
    cx = wp[0]; cy = wp[1]; cz = wp[2];
    if (blk == 0 && t == 0) {
      cent[it * 3 + 0] = cx; cent[it * 3 + 1] = cy; cent[it * 3 + 2] = cz;
    }
  }

  if (blk != 0) return;  // epilogue on block 0 of each batch only
  __syncthreads();

  // morton step 1: m = argmin_{j>=1} cdist(c0, cj), ref expansion formula
  if (t < GG) {
    float c0x = cent[0], c0y = cent[1], c0z = cent[2];
    float cjx = cent[t * 3 + 0], cjy = cent[t * 3 + 1], cjz = cent[t * 3 + 2];
    float sa = sq3(c0x, c0y, c0z);
    float sb = sq3(cjx, cjy, cjz);
    float dt = dot3(c0x, c0y, c0z, cjx, cjy, cjz);
    float dd = __fsub_rn(__fadd_rn(sa, sb), __fmul_rn(2.0f, dt));
    darr[t] = (t == 0) ? INFINITY : dd;
  }
  __syncthreads();
  if (t == 0) {
    float vd = darr[1]; int vi = 1;
    for (int j = 2; j < GG; ++j) {
      float od = darr[j];
      if (od < vd) { vd = od; vi = j; }  // strict < => first-min
    }
    msh[0] = vi;
    float* gc = ws + WS_GC + b * 6;
    gc[0] = cent[0];          gc[1] = cent[1];          gc[2] = cent[2];
    gc[3] = cent[vi * 3 + 0]; gc[4] = cent[vi * 3 + 1]; gc[5] = cent[vi * 3 + 2];
  }
  __syncthreads();
  int m = msh[0];
  // centroid output: pos0 = c0, pos1 = cm, pos>=2 = c0 (morton degeneracy)
  if (t < GG * 3) {
    int pos = t / 3, c = t % 3;
    float v = (pos == 1) ? cent[m * 3 + c] : cent[c];
    out[(size_t)b * GG * 3 + t] = v;
  }
}

// ---------------------------------------------------------------------------
// Kernel 2 (fused topk + encA): per group (32 blocks x 1024 threads):
// top-64 extraction into LDS xl, then f1 = relu(bn1(w1@x+b1)),
// f2 = w2@f1 + b2 -> global, fg = max_k f2 -> global.
// f1s overlays the dead darr region after a barrier.
// ---------------------------------------------------------------------------
__global__ void __launch_bounds__(NT1) k_grp(
    const float* __restrict__ points, float* __restrict__ ws,
    const float* __restrict__ w1, const float* __restrict__ b1,
    const float* __restrict__ g1, const float* __restrict__ be1,
    const float* __restrict__ m1, const float* __restrict__ v1,
    const float* __restrict__ w2, const float* __restrict__ b2) {
  extern __shared__ float smem[];
  float* darr = smem;                        // [NN] (topk) / f1s overlay (encA)
  float* f1s  = smem;                        // [128*65] = 8320 <= NN
  float* redd = smem + NN;                   // [2][16]
  int*   redi = (int*)(smem + NN + 32);      // [2][16]
  float* xl   = smem + NN + 64;              // [KK*3]

  const int g = blockIdx.x;
  const int b = g >> 1, which = g & 1;
  const int t = threadIdx.x;
  const float* P = points + (size_t)b * NN * 3;
  const float* gc = ws + WS_GC + b * 6 + which * 3;
  const float cx = gc[0], cy = gc[1], cz = gc[2];
  const float sa = sq3(cx, cy, cz);

  // ---- phase 1: top-64 extraction ----
  float bd = INFINITY; int bg = 0;
#pragma unroll
  for (int j = 0; j < PPT; ++j) {
    int p = t + j * NT1;
    const float* pp = P + (size_t)p * 3;
    float px = pp[0], py = pp[1], pz = pp[2];
    float sb = sq3(px, py, pz);
    float dt = dot3(cx, cy, cz, px, py, pz);
    float d  = __fsub_rn(__fadd_rn(sa, sb), __fmul_rn(2.0f, dt));
    darr[p] = d;
    if (d < bd) { bd = d; bg = p; }  // ascending p + strict < => first-min
  }
  int my_win = 0;
  for (int r = 0; r < KK; ++r) {
    float rd = bd; int ri = bg;
#pragma unroll
    for (int off = 1; off < 64; off <<= 1) {
      float od = __shfl_xor(rd, off);
      int   oi = __shfl_xor(ri, off);
      if (od < rd || (od == rd && oi < ri)) { rd = od; ri = oi; }
    }
    const int par = (r & 1) * 16;
    if ((t & 63) == 0) { redd[par + (t >> 6)] = rd; redi[par + (t >> 6)] = ri; }
    __syncthreads();
    int l = t & 15;
    float vd = redd[par + l]; int vi = redi[par + l];
#pragma unroll
    for (int off = 1; off < 16; off <<= 1) {
      float od = __shfl_xor(vd, off);
      int   oi = __shfl_xor(vi, off);
      if (od < vd || (od == vd && oi < vi)) { vd = od; vi = oi; }
    }
    if (t == r) my_win = vi;
    if (t == (vi & (NT1 - 1))) {  // owner invalidates + rescans its 32 slots
      darr[vi] = INFINITY;
      bd = INFINITY; bg = 0;
#pragma unroll
      for (int j = 0; j < PPT; ++j) {
        int p = t + j * NT1;
        float v = darr[p];
        if (v < bd) { bd = v; bg = p; }
      }
    }
  }
  __syncthreads();  // darr dead after this point
  if (t < KK) {     // thread t holds round-t winner; local coords into LDS
    const float* pp = P + (size_t)my_win * 3;
    xl[t * 3 + 0] = __fsub_rn(pp[0], cx);
    xl[t * 3 + 1] = __fsub_rn(pp[1], cy);
    xl[t * 3 + 2] = __fsub_rn(pp[2], cz);
  }
  __syncthreads();

  // ---- phase 2: f1 = relu(bn1(w1@x + b1)) -> f1s[128][65] ----
  {
    const int o = t & 127, kh = t >> 7;  // kh in [0,8)
    float wx = w1[o * 3 + 0], wy = w1[o * 3 + 1], wz = w1[o * 3 + 2];
    float inv = g1[o] * (1.0f / sqrtf(v1[o] + 1e-5f));
    float add = be1[o] - m1[o] * inv;
    float bb = b1[o];
#pragma unroll
    for (int kk = 0; kk < 8; ++kk) {
      int k = kh * 8 + kk;
      float f = fmaf(wx, xl[k * 3 + 0],
                fmaf(wy, xl[k * 3 + 1],
                fmaf(wz, xl[k * 3 + 2], bb)));
      f = fmaf(f, inv, add);
      f1s[o * 65 + k] = fmaxf(f, 0.0f);
    }
  }
  __syncthreads();

  // ---- phase 3: f2 = w2@f1 + b2 -> global; fg = max_k -> global ----
  const int k  = t & 63;
  const int og = __builtin_amdgcn_readfirstlane(t >> 6);  // wave-uniform [0,16)
  const int o0 = og * 16;
  float acc[16];
#pragma unroll
  for (int oo = 0; oo < 16; ++oo) acc[oo] = b2[o0 + oo];
  for (int i = 0; i < 128; ++i) {
    float xv = f1s[i * 65 + k];
#pragma unroll
    for (int oo = 0; oo < 16; ++oo)
      acc[oo] = fmaf(w2[(o0 + oo) * 128 + i], xv, acc[oo]);  // uniform -> s_load
  }
  float* f2g = ws + WS_F2 + (size_t)g * 256 * 64;
  float* fgg = ws + WS_FG + g * 256;
#pragma unroll
  for (int oo = 0; oo < 16; ++oo) f2g[(o0 + oo) * 64 + k] = acc[oo];
#pragma unroll
  for (int oo = 0; oo < 16; ++oo) {
    float v = acc[oo];
#pragma unroll
    for (int off = 1; off < 64; off <<= 1) v = fmaxf(v, __shfl_xor(v, off));
    if (k == 0) fgg[o0 + oo] = v;
  }
}

// ---------------------------------------------------------------------------
// Kernel 3 (stage B): f4 = relu(bn2(w3 @ concat([fg bcast, f2]) + b3))
// grid = 32 groups x 8 o-chunks of 64.
// ---------------------------------------------------------------------------
__global__ void __launch_bounds__(256) k_encB(
    float* __restrict__ ws,
    const float* __restrict__ w3, const float* __restrict__ b3,
    const float* __restrict__ g2, const float* __restrict__ be2,
    const float* __restrict__ m2, const float* __restrict__ v2) {
  __shared__ float part[4][64];
  __shared__ float sfg[64];
  const int blk = blockIdx.x;
  const int g = blk >> 3, oc = blk & 7;
  const int t = threadIdx.x;
  const int k = t & 63;
  const int og = __builtin_amdgcn_readfirstlane(t >> 6);
  const int ob = oc * 64;
  const float* fgg = ws + WS_FG + g * 256;
  {  // k-independent part: sum_{i<256} w3[o][i] * fg[i]
    int o = ob + k;
    float s = 0.0f;
    int i0 = og * 64;
    for (int ii = 0; ii < 64; ++ii) {
      int i = i0 + ii;
      s = fmaf(w3[(size_t)o * 512 + i], fgg[i], s);
    }
    part[og][k] = s;
  }
  __syncthreads();
  if (t < 64)
    sfg[t] = b3[ob + t] + ((part[0][t] + part[1][t]) + (part[2][t] + part[3][t]));
  __syncthreads();
  const int o0 = ob + og * 16;
  float acc[16];
#pragma unroll
  for (int oo = 0; oo < 16; ++oo) acc[oo] = sfg[og * 16 + oo];
  const float* f2g = ws + WS_F2 + (size_t)g * 256 * 64;
#pragma unroll 4
  for (int i = 0; i < 256; ++i) {
    float xv = f2g[i * 64 + k];
#pragma unroll
    for (int oo = 0; oo < 16; ++oo)
      acc[oo] = fmaf(w3[(size_t)(o0 + oo) * 512 + 256 + i], xv, acc[oo]);
  }
  float* f4g = ws + WS_F4 + (size_t)g * 512 * 64;
#pragma unroll
  for (int oo = 0; oo < 16; ++oo) {
    int o = o0 + oo;
    float inv = g2[o] * (1.0f / sqrtf(v2[o] + 1e-5f));
    float add = be2[o] - m2[o] * inv;
    f4g[o * 64 + k] = fmaxf(fmaf(acc[oo], inv, add), 0.0f);
  }
}

// ---------------------------------------------------------------------------
// Kernel 4 (fused stage C + broadcast): token = max_k (w4 @ f4 + b4), written
// directly to all output positions (xor butterfly leaves max in ALL lanes;
// lanes scatter positions). grid = 32 x 12 chunks of 32.
// ---------------------------------------------------------------------------
__global__ void __launch_bounds__(256) k_encCb(float* __restrict__ ws,
                                               const float* __restrict__ w4,
                                               const float* __restrict__ b4,
                                               float* __restrict__ out) {
  const int blk = blockIdx.x;
  const int g = blk / 12, oc = blk % 12;
  const int b = g >> 1, which = g & 1;
  const int t = threadIdx.x;
  const int k = t & 63;
  const int og = __builtin_amdgcn_readfirstlane(t >> 6);
  const int o0 = oc * 32 + og * 8;
  float acc[8];
#pragma unroll
  for (int oo = 0; oo < 8; ++oo) acc[oo] = b4[o0 + oo];
  const float* f4g = ws + WS_F4 + (size_t)g * 512 * 64;
#pragma unroll 8
  for (int i = 0; i < 512; ++i) {
    float xv = f4g[i * 64 + k];
#pragma unroll
    for (int oo = 0; oo < 8; ++oo)
      acc[oo] = fmaf(w4[(size_t)(o0 + oo) * 512 + i], xv, acc[oo]);
  }
#pragma unroll
  for (int oo = 0; oo < 8; ++oo) {
#pragma unroll
    for (int off = 1; off < 64; off <<= 1)
      acc[oo] = fmaxf(acc[oo], __shfl_xor(acc[oo], off));
  }
  // all lanes now hold the per-oo max; scatter to output positions
  float* tok = out + (size_t)BB * GG * 3;
  if (which == 1) {
    if (k == 0) {
      float* dst = tok + ((size_t)b * GG + 1) * EDD + o0;
#pragma unroll
      for (int oo = 0; oo < 8; ++oo) dst[oo] = acc[oo];
    }
  } else {
#pragma unroll
    for (int rep = 0; rep < 2; ++rep) {
      int pos = k + rep * 64;
      if (pos == 1) continue;
      float* dst = tok + ((size_t)b * GG + pos) * EDD + o0;
#pragma unroll
      for (int oo = 0; oo < 8; ++oo) dst[oo] = acc[oo];
    }
  }
}

extern "C" void kernel_launch(void* const* d_in, const int* in_sizes, int n_in,
                              void* d_out, int out_size, void* d_ws, size_t ws_size,
                              hipStream_t stream) {
  const float* points = (const float*)d_in[0];
  const float* w1  = (const float*)d_in[1];
  const float* b1  = (const float*)d_in[2];
  const float* g1  = (const float*)d_in[3];
  const float* be1 = (const float*)d_in[4];
  const float* m1  = (const float*)d_in[5];
  const float* v1  = (const float*)d_in[6];
  const float* w2  = (const float*)d_in[7];
  const float* b2  = (const float*)d_in[8];
  const float* w3  = (const float*)d_in[9];
  const float* b3  = (const float*)d_in[10];
  const float* g2  = (const float*)d_in[11];
  const float* be2 = (const float*)d_in[12];
  const float* m2  = (const float*)d_in[13];
  const float* v2  = (const float*)d_in[14];
  const float* w4  = (const float*)d_in[15];
  const float* b4  = (const float*)d_in[16];
  float* out = (float*)d_out;
  float* ws  = (float*)d_ws;

  // dynamic LDS >64KB needs the opt-in attr (host-side, graph-safe, idempotent)
  size_t dyn_grp = (size_t)(NN + 64 + KK * 3 + 16) * sizeof(float);
  hipFuncSetAttribute(reinterpret_cast<const void*>(k_grp),
                      hipFuncAttributeMaxDynamicSharedMemorySize, (int)dyn_grp);

  // invalidate k_fps sync slots (tag field becomes 0xAAAA != any round);
  // re-runs every graph iteration so stale tags from prior runs can't alias.
  hipMemsetAsync(ws + WS_SYNC, 0xAA, (size_t)2 * 16 * 64 * 8, stream);

  hipLaunchKernelGGL(k_fps, dim3(BB * SB), dim3(NT1), 0, stream,
                     points, out, ws);
  hipLaunchKernelGGL(k_grp, dim3(32), dim3(NT1), dyn_grp, stream,
                     points, ws, w1, b1, g1, be1, m1, v1, w2, b2);
  hipLaunchKernelGGL(k_encB, dim3(256), dim3(256), 0, stream,
                     ws, w3, b3, g2, be2, m2, v2);
  hipLaunchKernelGGL(k_encCb, dim3(384), dim3(256), 0, stream, ws, w4, b4, out);
}